// Round 1
// baseline (835.254 us; speedup 1.0000x reference)
//
#include <hip/hip_runtime.h>
#include <hip/hip_bf16.h>
#include <math.h>

#define B 64
#define S 1024
#define D 1024
#define C 10
#define TD 3072  // 3*D

__device__ __forceinline__ float wave_sum(float v) {
    #pragma unroll
    for (int off = 32; off > 0; off >>= 1) v += __shfl_down(v, off, 64);
    return v;  // valid on lane 0
}

__device__ __forceinline__ float sigm(float x) { return 1.0f / (1.0f + expf(-x)); }

// logits[b,s] = dot(feat[b,s,:], a_w)   — one wave per row, float4 loads
__global__ void k_logits(const float* __restrict__ feat, const float* __restrict__ a_w,
                         float* __restrict__ logits) {
    int tid = threadIdx.x;
    int wv = tid >> 6, lane = tid & 63;
    int row = blockIdx.x * 4 + wv;  // < B*S
    const float* base = feat + (size_t)row * D;
    float acc = 0.f;
    #pragma unroll
    for (int p = 0; p < 4; ++p) {
        int k = p * 256 + lane * 4;
        const float4 f = *reinterpret_cast<const float4*>(base + k);
        const float4 a = *reinterpret_cast<const float4*>(a_w + k);
        acc += f.x * a.x + f.y * a.y + f.z * a.z + f.w * a.w;
    }
    acc = wave_sum(acc);
    if (lane == 0) logits[row] = acc;
}

// softmax over S per batch, in place (logits -> weights)
__global__ void k_softmax(float* __restrict__ wbuf) {
    int b = blockIdx.x, tid = threadIdx.x;
    int wv = tid >> 6, lane = tid & 63;
    float l[4];
    #pragma unroll
    for (int i = 0; i < 4; ++i) l[i] = wbuf[b * S + tid + i * 256];
    float m = fmaxf(fmaxf(l[0], l[1]), fmaxf(l[2], l[3]));
    #pragma unroll
    for (int off = 32; off > 0; off >>= 1) m = fmaxf(m, __shfl_xor(m, off, 64));
    __shared__ float sm[4], ss[4];
    if (lane == 0) sm[wv] = m;
    __syncthreads();
    float M = fmaxf(fmaxf(sm[0], sm[1]), fmaxf(sm[2], sm[3]));
    float p[4]; float lsum = 0.f;
    #pragma unroll
    for (int i = 0; i < 4; ++i) { p[i] = expf(l[i] - M); lsum += p[i]; }
    #pragma unroll
    for (int off = 32; off > 0; off >>= 1) lsum += __shfl_xor(lsum, off, 64);
    if (lane == 0) ss[wv] = lsum;
    __syncthreads();
    float inv = 1.0f / (ss[0] + ss[1] + ss[2] + ss[3]);
    #pragma unroll
    for (int i = 0; i < 4; ++i) wbuf[b * S + tid + i * 256] = p[i] * inv;
}

// partial pooled: part[b][chunk][d] = sum_{s in chunk} w[b,s]*feat[b,s,d]
__global__ void k_pool_part(const float* __restrict__ feat, const float* __restrict__ w,
                            float* __restrict__ part) {
    int d = blockIdx.x * 256 + threadIdx.x;
    int chunk = blockIdx.y, b = blockIdx.z;
    int s0 = chunk * 256;
    const float* wb = w + b * S + s0;
    const float* fb = feat + ((size_t)b * S + s0) * D + d;
    float acc = 0.f;
    for (int s = 0; s < 256; ++s) acc += wb[s] * fb[(size_t)s * D];
    part[(b * 4 + chunk) * D + d] = acc;
}

__global__ void k_pool_reduce(const float* __restrict__ part, float* __restrict__ pooled) {
    int idx = blockIdx.x * 256 + threadIdx.x;  // < B*D
    int b = idx >> 10, d = idx & 1023;
    pooled[idx] = part[(b * 4 + 0) * D + d] + part[(b * 4 + 1) * D + d] +
                  part[(b * 4 + 2) * D + d] + part[(b * 4 + 3) * D + d];
}

// out[k*TD + j] = in[j*stride + k],  j<TD(=3072), k<D(=1024)
__global__ void k_transpose(const float* __restrict__ in, float* __restrict__ out, int stride) {
    __shared__ float tile[32][33];
    int kt = blockIdx.x, jt = blockIdx.y;
    int tx = threadIdx.x, ty = threadIdx.y;  // 32 x 8
    #pragma unroll
    for (int i = 0; i < 4; ++i) {
        int j = jt * 32 + ty + i * 8, k = kt * 32 + tx;
        tile[ty + i * 8][tx] = in[(size_t)j * stride + k];
    }
    __syncthreads();
    #pragma unroll
    for (int i = 0; i < 4; ++i) {
        int k = kt * 32 + ty + i * 8, j = jt * 32 + tx;
        out[(size_t)k * TD + j] = tile[tx][ty + i * 8];
    }
}

__global__ void k_wscore(const float* __restrict__ W_ih, float* __restrict__ wscore) {
    int j = blockIdx.x * 256 + threadIdx.x;
    if (j < TD) wscore[j] = W_ih[(size_t)j * (D + 1) + D];
}

// gi0[b][j] = dot(pooled[b,:], W_ih[j,:D]) + b_ih[j]  (via WihT), 8 batches/block
__global__ void k_gi0(const float* __restrict__ WihT, const float* __restrict__ pooled,
                      const float* __restrict__ b_ih, float* __restrict__ gi0) {
    __shared__ float sh[8][256];
    int tid = threadIdx.x;
    int j = blockIdx.x * 256 + tid;
    int bg = blockIdx.y;  // 8 groups of 8 batches
    float acc[8] = {0, 0, 0, 0, 0, 0, 0, 0};
    for (int kc = 0; kc < D; kc += 256) {
        #pragma unroll
        for (int i = 0; i < 8; ++i) sh[i][tid] = pooled[(bg * 8 + i) * D + kc + tid];
        __syncthreads();
        for (int kk = 0; kk < 256; ++kk) {
            float wv = WihT[(size_t)(kc + kk) * TD + j];
            #pragma unroll
            for (int i = 0; i < 8; ++i) acc[i] += sh[i][kk] * wv;
        }
        __syncthreads();
    }
    float bb = b_ih[j];
    #pragma unroll
    for (int i = 0; i < 8; ++i) gi0[(bg * 8 + i) * TD + j] = acc[i] + bb;
}

// One GRU step. Grid (16 d-tiles, 16 batch-groups of 4), block 256 (wave = one batch).
__global__ void k_step(const float* __restrict__ WhhT, const float* __restrict__ b_hh,
                       const float* __restrict__ gi0, const float* __restrict__ wscore,
                       const float* __restrict__ W_out, const float* __restrict__ b_out,
                       const float* __restrict__ h_in, float* __restrict__ h_out,
                       float* __restrict__ spart, int t) {
    int tid = threadIdx.x;
    int wv = tid >> 6, lane = tid & 63;
    int dt = blockIdx.x;              // 0..15
    int b = blockIdx.y * 4 + wv;      // 0..63
    int d = dt * 64 + lane;

    // score_{t} = sigmoid(sum of previous step's partial dots + b_out); 0 at t==0
    float score = 0.f;
    if (t > 0) {
        float s = b_out[0];
        const float* sp = spart + ((t - 1) * B + b) * 16;
        #pragma unroll
        for (int i = 0; i < 16; ++i) s += sp[i];
        score = sigm(s);
    }

    float accr = 0.f, accz = 0.f, accn = 0.f, hprev = 0.f;
    if (t > 0) {
        const float* hb = h_in + b * D;
        const float* w0 = WhhT + d;
        #pragma unroll 4
        for (int k = 0; k < D; ++k) {
            float hv = hb[k];  // uniform within wave -> broadcast
            const float* wk = w0 + (size_t)k * TD;
            accr += hv * wk[0];
            accz += hv * wk[D];
            accn += hv * wk[2 * D];
        }
        hprev = hb[d];
    }
    float ghr = accr + b_hh[d];
    float ghz = accz + b_hh[D + d];
    float ghn = accn + b_hh[2 * D + d];
    const float* gb = gi0 + b * TD;
    float gir = gb[d]         + score * wscore[d];
    float giz = gb[D + d]     + score * wscore[D + d];
    float gin = gb[2 * D + d] + score * wscore[2 * D + d];
    float r = sigm(gir + ghr);
    float z = sigm(giz + ghz);
    float n = tanhf(gin + r * ghn);
    float hnew = (1.f - z) * n + z * hprev;
    h_out[b * D + d] = hnew;

    float partial = hnew * W_out[d];
    partial = wave_sum(partial);
    if (lane == 0) spart[(t * B + b) * 16 + dt] = partial;
}

__global__ void k_final(const float* __restrict__ spart, const float* __restrict__ b_out,
                        float* __restrict__ out) {
    int i = blockIdx.x * 256 + threadIdx.x;
    if (i >= B * C) return;
    int b = i / C, t = i % C;
    float s = b_out[0];
    const float* sp = spart + (t * B + b) * 16;
    #pragma unroll
    for (int k = 0; k < 16; ++k) s += sp[k];
    out[i] = sigm(s);
}

extern "C" void kernel_launch(void* const* d_in, const int* in_sizes, int n_in,
                              void* d_out, int out_size, void* d_ws, size_t ws_size,
                              hipStream_t stream) {
    const float* feat  = (const float*)d_in[0];
    const float* a_w   = (const float*)d_in[1];
    const float* W_ih  = (const float*)d_in[2];
    const float* W_hh  = (const float*)d_in[3];
    const float* b_ih  = (const float*)d_in[4];
    const float* b_hh  = (const float*)d_in[5];
    const float* W_out = (const float*)d_in[6];
    const float* b_out = (const float*)d_in[7];
    float* out = (float*)d_out;
    float* ws = (float*)d_ws;

    float* wbuf   = ws;                         // B*S
    float* part   = wbuf + B * S;               // 4*B*D
    float* pooled = part + 4 * B * D;           // B*D
    float* WihT   = pooled + B * D;             // D*TD
    float* wscore = WihT + (size_t)D * TD;      // TD
    float* WhhT   = wscore + TD;                // D*TD
    float* gi0    = WhhT + (size_t)D * TD;      // B*TD
    float* h0     = gi0 + B * TD;               // B*D
    float* h1     = h0 + B * D;                 // B*D
    float* spart  = h1 + B * D;                 // C*B*16

    k_logits<<<dim3(B * S / 4), 256, 0, stream>>>(feat, a_w, wbuf);
    k_softmax<<<dim3(B), 256, 0, stream>>>(wbuf);
    k_pool_part<<<dim3(4, 4, B), 256, 0, stream>>>(feat, wbuf, part);
    k_pool_reduce<<<dim3(B * D / 256), 256, 0, stream>>>(part, pooled);
    k_transpose<<<dim3(32, 96), dim3(32, 8), 0, stream>>>(W_ih, WihT, D + 1);
    k_wscore<<<dim3(12), 256, 0, stream>>>(W_ih, wscore);
    k_transpose<<<dim3(32, 96), dim3(32, 8), 0, stream>>>(W_hh, WhhT, D);
    k_gi0<<<dim3(12, 8), 256, 0, stream>>>(WihT, pooled, b_ih, gi0);

    float* hb[2] = {h0, h1};
    for (int t = 0; t < C; ++t) {
        k_step<<<dim3(16, 16), 256, 0, stream>>>(WhhT, b_hh, gi0, wscore, W_out, b_out,
                                                 hb[t & 1], hb[(t + 1) & 1], spart, t);
    }
    k_final<<<dim3((B * C + 255) / 256), 256, 0, stream>>>(spart, b_out, out);
}

// Round 2
// 566.523 us; speedup vs baseline: 1.4744x; 1.4744x over previous
//
#include <hip/hip_runtime.h>
#include <hip/hip_bf16.h>
#include <math.h>

#define B 64
#define S 1024
#define D 1024
#define C 10
#define TD 3072  // 3*D

__device__ __forceinline__ float wave_sum_bc(float v) {  // result on ALL lanes
    #pragma unroll
    for (int off = 1; off < 64; off <<= 1) v += __shfl_xor(v, off, 64);
    return v;
}
__device__ __forceinline__ float wave_sum(float v) {  // result on lane 0
    #pragma unroll
    for (int off = 32; off > 0; off >>= 1) v += __shfl_down(v, off, 64);
    return v;
}
__device__ __forceinline__ float sigm(float x) { return 1.0f / (1.0f + expf(-x)); }

// ---------------------------------------------------------------------------
// Online-softmax pooling, single pass over feat.
// grid (16 chunks, B), block 256 = 4 waves; wave handles 16 rows of 64-row chunk.
// Lane l owns cols {r*256 + l*4 .. +3}, r=0..3 (16 cols in registers).
__global__ void k_pool_part(const float* __restrict__ feat, const float* __restrict__ a_w,
                            float* __restrict__ part, float* __restrict__ ml) {
    int ch = blockIdx.x, b = blockIdx.y;
    int tid = threadIdx.x, w = tid >> 6, lane = tid & 63;
    float4 aw[4], acc[4];
    #pragma unroll
    for (int r = 0; r < 4; ++r) {
        aw[r] = *reinterpret_cast<const float4*>(&a_w[r * 256 + lane * 4]);
        acc[r] = make_float4(0.f, 0.f, 0.f, 0.f);
    }
    float m = -INFINITY, l = 0.f;
    const float* fb = feat + ((size_t)b * S + ch * 64 + w * 16) * D;
    for (int i = 0; i < 16; ++i) {
        float4 f[4];
        #pragma unroll
        for (int r = 0; r < 4; ++r)
            f[r] = *reinterpret_cast<const float4*>(&fb[(size_t)i * D + r * 256 + lane * 4]);
        float dot = 0.f;
        #pragma unroll
        for (int r = 0; r < 4; ++r)
            dot += f[r].x * aw[r].x + f[r].y * aw[r].y + f[r].z * aw[r].z + f[r].w * aw[r].w;
        dot = wave_sum_bc(dot);  // wave-uniform
        if (dot <= m) {
            float wg = expf(dot - m);
            l += wg;
            #pragma unroll
            for (int r = 0; r < 4; ++r) {
                acc[r].x += wg * f[r].x; acc[r].y += wg * f[r].y;
                acc[r].z += wg * f[r].z; acc[r].w += wg * f[r].w;
            }
        } else {
            float sc = expf(m - dot);  // exp(-inf)=0 handles first row
            l = l * sc + 1.f;
            #pragma unroll
            for (int r = 0; r < 4; ++r) {
                acc[r].x = acc[r].x * sc + f[r].x; acc[r].y = acc[r].y * sc + f[r].y;
                acc[r].z = acc[r].z * sc + f[r].z; acc[r].w = acc[r].w * sc + f[r].w;
            }
            m = dot;
        }
    }
    __shared__ float sacc[4][1024];
    __shared__ float sml[4][2];
    #pragma unroll
    for (int r = 0; r < 4; ++r)
        *reinterpret_cast<float4*>(&sacc[w][r * 256 + lane * 4]) = acc[r];
    if (lane == 0) { sml[w][0] = m; sml[w][1] = l; }
    __syncthreads();
    float m0 = sml[0][0], m1 = sml[1][0], m2 = sml[2][0], m3 = sml[3][0];
    float mg = fmaxf(fmaxf(m0, m1), fmaxf(m2, m3));
    float s0 = expf(m0 - mg), s1 = expf(m1 - mg), s2 = expf(m2 - mg), s3 = expf(m3 - mg);
    int c = tid * 4;
    float4 a0 = *reinterpret_cast<float4*>(&sacc[0][c]);
    float4 a1 = *reinterpret_cast<float4*>(&sacc[1][c]);
    float4 a2 = *reinterpret_cast<float4*>(&sacc[2][c]);
    float4 a3 = *reinterpret_cast<float4*>(&sacc[3][c]);
    float4 o;
    o.x = s0 * a0.x + s1 * a1.x + s2 * a2.x + s3 * a3.x;
    o.y = s0 * a0.y + s1 * a1.y + s2 * a2.y + s3 * a3.y;
    o.z = s0 * a0.z + s1 * a1.z + s2 * a2.z + s3 * a3.z;
    o.w = s0 * a0.w + s1 * a1.w + s2 * a2.w + s3 * a3.w;
    *reinterpret_cast<float4*>(&part[((size_t)b * 16 + ch) * D + c]) = o;
    if (tid == 0) {
        float lg = s0 * sml[0][1] + s1 * sml[1][1] + s2 * sml[2][1] + s3 * sml[3][1];
        ml[(b * 16 + ch) * 2] = mg;
        ml[(b * 16 + ch) * 2 + 1] = lg;
    }
}

// Combine 16 chunk-partials -> pooled[b][d]. grid (B), block 256.
__global__ void k_pool_comb(const float* __restrict__ part, const float* __restrict__ ml,
                            float* __restrict__ pooled) {
    int b = blockIdx.x, tid = threadIdx.x;
    float mg = -INFINITY;
    #pragma unroll
    for (int i = 0; i < 16; ++i) mg = fmaxf(mg, ml[(b * 16 + i) * 2]);
    float denom = 0.f, sc[16];
    #pragma unroll
    for (int i = 0; i < 16; ++i) {
        sc[i] = expf(ml[(b * 16 + i) * 2] - mg);
        denom += sc[i] * ml[(b * 16 + i) * 2 + 1];
    }
    float inv = 1.f / denom;
    int c = tid * 4;
    float4 o = make_float4(0.f, 0.f, 0.f, 0.f);
    #pragma unroll
    for (int i = 0; i < 16; ++i) {
        float4 p = *reinterpret_cast<const float4*>(&part[((size_t)b * 16 + i) * D + c]);
        o.x += sc[i] * p.x; o.y += sc[i] * p.y; o.z += sc[i] * p.z; o.w += sc[i] * p.w;
    }
    o.x *= inv; o.y *= inv; o.z *= inv; o.w *= inv;
    *reinterpret_cast<float4*>(&pooled[(size_t)b * D + c]) = o;
}

// Transpose W[j][k] (j<TD, k<D, row stride `stride`) into gate-interleaved quads:
// W3 quad index (k4*D + dd)*3 + g holds W[g*D+dd][k4*4 .. +3].
__global__ void k_transpose3(const float* __restrict__ in, float* __restrict__ out, int stride) {
    __shared__ float tile[32][33];
    int kt = blockIdx.x, jt = blockIdx.y;
    int tx = threadIdx.x, ty = threadIdx.y;  // 32 x 8
    #pragma unroll
    for (int i = 0; i < 4; ++i) {
        int j = jt * 32 + ty + i * 8, k = kt * 32 + tx;
        tile[ty + i * 8][tx] = in[(size_t)j * stride + k];
    }
    __syncthreads();
    int g  = jt >> 5;                    // which gate (j / 1024), 32-tiles don't straddle
    int dd = ((jt & 31) << 5) + tx;      // d within gate
    int k4 = kt * 8 + ty;                // k quad index
    float4 v;
    v.x = tile[tx][ty * 4 + 0];
    v.y = tile[tx][ty * 4 + 1];
    v.z = tile[tx][ty * 4 + 2];
    v.w = tile[tx][ty * 4 + 3];
    *reinterpret_cast<float4*>(&out[(((size_t)k4 * D + dd) * 3 + g) * 4]) = v;
}

__global__ void k_wscore(const float* __restrict__ W_ih, float* __restrict__ wscore) {
    int j = blockIdx.x * 256 + threadIdx.x;
    if (j < TD) wscore[j] = W_ih[(size_t)j * (D + 1) + D];
}

// gi0[b][j] = dot(pooled[b,:], W_ih[j,:D]) + b_ih[j], via W3ih.
// grid 256 (XCD-swizzled -> dt 0..15, bg 0..15), block 1024 = 16 waves (4 bsub x 4 ks).
__global__ __launch_bounds__(1024, 4) void k_gi0b(const float* __restrict__ W3,
        const float* __restrict__ pooled, const float* __restrict__ b_ih,
        float* __restrict__ gi0) {
    __shared__ float hsh[4][1024];
    __shared__ float psh[16][3][64];
    int n = blockIdx.x, xcd = n & 7, slot = n >> 3;
    int dt = xcd * 2 + (slot & 1), bg = slot >> 1;
    int tid = threadIdx.x, w = tid >> 6, lane = tid & 63;
    int bsub = w >> 2, ks = w & 3, b = bg * 4 + bsub, d = dt * 64 + lane;
    {
        int r = tid >> 8, c = (tid & 255) * 4;
        *reinterpret_cast<float4*>(&hsh[r][c]) =
            *reinterpret_cast<const float4*>(&pooled[(size_t)(bg * 4 + r) * D + c]);
    }
    __syncthreads();
    float accr = 0.f, accz = 0.f, accn = 0.f;
    const float4* wp = reinterpret_cast<const float4*>(W3) + ((size_t)(ks * 64) * D + d) * 3;
    #pragma unroll 4
    for (int kk = 0; kk < 64; ++kk) {
        float4 hq = *reinterpret_cast<const float4*>(&hsh[bsub][(ks * 64 + kk) * 4]);
        float4 wr = wp[0], wz = wp[1], wn = wp[2];
        accr += hq.x * wr.x + hq.y * wr.y + hq.z * wr.z + hq.w * wr.w;
        accz += hq.x * wz.x + hq.y * wz.y + hq.z * wz.z + hq.w * wz.w;
        accn += hq.x * wn.x + hq.y * wn.y + hq.z * wn.z + hq.w * wn.w;
        wp += (size_t)D * 3;
    }
    psh[w][0][lane] = accr; psh[w][1][lane] = accz; psh[w][2][lane] = accn;
    __syncthreads();
    if (ks == 0) {
        int wb = bsub * 4;
        float gr = psh[wb][0][lane] + psh[wb + 1][0][lane] + psh[wb + 2][0][lane] + psh[wb + 3][0][lane];
        float gz = psh[wb][1][lane] + psh[wb + 1][1][lane] + psh[wb + 2][1][lane] + psh[wb + 3][1][lane];
        float gn = psh[wb][2][lane] + psh[wb + 1][2][lane] + psh[wb + 2][2][lane] + psh[wb + 3][2][lane];
        gi0[(size_t)b * TD + d]          = gr + b_ih[d];
        gi0[(size_t)b * TD + D + d]      = gz + b_ih[D + d];
        gi0[(size_t)b * TD + 2 * D + d]  = gn + b_ih[2 * D + d];
    }
}

// One GRU step, fused dot + gates. Same geometry as k_gi0b.
__global__ __launch_bounds__(1024, 4) void k_step(const float* __restrict__ W3,
        const float* __restrict__ b_hh, const float* __restrict__ gi0,
        const float* __restrict__ wscore, const float* __restrict__ W_out,
        const float* __restrict__ b_out, const float* __restrict__ h_in,
        float* __restrict__ h_out, float* __restrict__ spart, int t) {
    __shared__ float hsh[4][1024];
    __shared__ float psh[16][3][64];
    int n = blockIdx.x, xcd = n & 7, slot = n >> 3;
    int dt = xcd * 2 + (slot & 1), bg = slot >> 1;
    int tid = threadIdx.x, w = tid >> 6, lane = tid & 63;
    int bsub = w >> 2, ks = w & 3, b = bg * 4 + bsub, d = dt * 64 + lane;
    if (t > 0) {
        int r = tid >> 8, c = (tid & 255) * 4;
        *reinterpret_cast<float4*>(&hsh[r][c]) =
            *reinterpret_cast<const float4*>(&h_in[(size_t)(bg * 4 + r) * D + c]);
    }
    __syncthreads();
    float accr = 0.f, accz = 0.f, accn = 0.f;
    if (t > 0) {
        const float4* wp = reinterpret_cast<const float4*>(W3) + ((size_t)(ks * 64) * D + d) * 3;
        #pragma unroll 4
        for (int kk = 0; kk < 64; ++kk) {
            float4 hq = *reinterpret_cast<const float4*>(&hsh[bsub][(ks * 64 + kk) * 4]);
            float4 wr = wp[0], wz = wp[1], wn = wp[2];
            accr += hq.x * wr.x + hq.y * wr.y + hq.z * wr.z + hq.w * wr.w;
            accz += hq.x * wz.x + hq.y * wz.y + hq.z * wz.z + hq.w * wz.w;
            accn += hq.x * wn.x + hq.y * wn.y + hq.z * wn.z + hq.w * wn.w;
            wp += (size_t)D * 3;
        }
    }
    psh[w][0][lane] = accr; psh[w][1][lane] = accz; psh[w][2][lane] = accn;
    __syncthreads();
    if (ks == 0) {
        int wb = bsub * 4;
        float gr = psh[wb][0][lane] + psh[wb + 1][0][lane] + psh[wb + 2][0][lane] + psh[wb + 3][0][lane];
        float gz = psh[wb][1][lane] + psh[wb + 1][1][lane] + psh[wb + 2][1][lane] + psh[wb + 3][1][lane];
        float gn = psh[wb][2][lane] + psh[wb + 1][2][lane] + psh[wb + 2][2][lane] + psh[wb + 3][2][lane];
        float score = 0.f;
        if (t > 0) {
            float s = b_out[0];
            const float* sp = spart + ((size_t)(t - 1) * B + b) * 16;
            #pragma unroll
            for (int i = 0; i < 16; ++i) s += sp[i];
            score = sigm(s);
        }
        float ghr = gr + b_hh[d];
        float ghz = gz + b_hh[D + d];
        float ghn = gn + b_hh[2 * D + d];
        const float* gb = gi0 + (size_t)b * TD;
        float gir = gb[d]         + score * wscore[d];
        float giz = gb[D + d]     + score * wscore[D + d];
        float gin = gb[2 * D + d] + score * wscore[2 * D + d];
        float rr = sigm(gir + ghr);
        float zz = sigm(giz + ghz);
        float nn = tanhf(gin + rr * ghn);
        float hprev = (t > 0) ? hsh[bsub][d] : 0.f;
        float hnew = (1.f - zz) * nn + zz * hprev;
        h_out[(size_t)b * D + d] = hnew;
        float pt = wave_sum(hnew * W_out[d]);
        if (lane == 0) spart[((size_t)t * B + b) * 16 + dt] = pt;
    }
}

__global__ void k_final(const float* __restrict__ spart, const float* __restrict__ b_out,
                        float* __restrict__ out) {
    int i = blockIdx.x * 256 + threadIdx.x;
    if (i >= B * C) return;
    int b = i / C, t = i % C;
    float s = b_out[0];
    const float* sp = spart + ((size_t)t * B + b) * 16;
    #pragma unroll
    for (int k = 0; k < 16; ++k) s += sp[k];
    out[i] = sigm(s);
}

extern "C" void kernel_launch(void* const* d_in, const int* in_sizes, int n_in,
                              void* d_out, int out_size, void* d_ws, size_t ws_size,
                              hipStream_t stream) {
    const float* feat  = (const float*)d_in[0];
    const float* a_w   = (const float*)d_in[1];
    const float* W_ih  = (const float*)d_in[2];
    const float* W_hh  = (const float*)d_in[3];
    const float* b_ih  = (const float*)d_in[4];
    const float* b_hh  = (const float*)d_in[5];
    const float* W_out = (const float*)d_in[6];
    const float* b_out = (const float*)d_in[7];
    float* out = (float*)d_out;
    float* ws = (float*)d_ws;

    float* part   = ws;                          // B*16*D
    float* ml     = part + (size_t)B * 16 * D;   // B*16*2
    float* pooled = ml + B * 16 * 2;             // B*D
    float* W3ih   = pooled + B * D;              // D*TD
    float* wscore = W3ih + (size_t)D * TD;       // TD
    float* W3hh   = wscore + TD;                 // D*TD
    float* gi0    = W3hh + (size_t)D * TD;       // B*TD
    float* h0     = gi0 + (size_t)B * TD;        // B*D
    float* h1     = h0 + B * D;                  // B*D
    float* spart  = h1 + B * D;                  // C*B*16

    k_pool_part<<<dim3(16, B), 256, 0, stream>>>(feat, a_w, part, ml);
    k_pool_comb<<<dim3(B), 256, 0, stream>>>(part, ml, pooled);
    k_transpose3<<<dim3(32, 96), dim3(32, 8), 0, stream>>>(W_ih, W3ih, D + 1);
    k_wscore<<<dim3(12), 256, 0, stream>>>(W_ih, wscore);
    k_transpose3<<<dim3(32, 96), dim3(32, 8), 0, stream>>>(W_hh, W3hh, D);
    k_gi0b<<<dim3(256), 1024, 0, stream>>>(W3ih, pooled, b_ih, gi0);

    float* hb[2] = {h0, h1};
    for (int t = 0; t < C; ++t) {
        k_step<<<dim3(256), 1024, 0, stream>>>(W3hh, b_hh, gi0, wscore, W_out, b_out,
                                               hb[t & 1], hb[(t + 1) & 1], spart, t);
    }
    k_final<<<dim3((B * C + 255) / 256), 256, 0, stream>>>(spart, b_out, out);
}

// Round 3
// 144.481 us; speedup vs baseline: 5.7811x; 3.9211x over previous
//
#include <hip/hip_runtime.h>
#include <hip/hip_bf16.h>
#include <math.h>

#define B 64
#define S 1024
#define D 1024
#define C 10
#define TD 3072  // 3*D

typedef __attribute__((ext_vector_type(8))) short s8v;   // 8 bf16 (A/B frag)
typedef __attribute__((ext_vector_type(4))) float f4v;   // 4 f32  (C/D frag)

__device__ __forceinline__ float wave_sum_bc(float v) {
    #pragma unroll
    for (int off = 1; off < 64; off <<= 1) v += __shfl_xor(v, off, 64);
    return v;
}
__device__ __forceinline__ float sigm(float x) { return 1.0f / (1.0f + expf(-x)); }
__device__ __forceinline__ short f2bf(float f) {
    __hip_bfloat16 h = __float2bfloat16(f);
    return *reinterpret_cast<short*>(&h);
}

// ---------------------------------------------------------------------------
// Online-softmax pooling, single pass over feat (unchanged from r2 — passed).
__global__ void k_pool_part(const float* __restrict__ feat, const float* __restrict__ a_w,
                            float* __restrict__ part, float* __restrict__ ml) {
    int ch = blockIdx.x, b = blockIdx.y;
    int tid = threadIdx.x, w = tid >> 6, lane = tid & 63;
    float4 aw[4], acc[4];
    #pragma unroll
    for (int r = 0; r < 4; ++r) {
        aw[r] = *reinterpret_cast<const float4*>(&a_w[r * 256 + lane * 4]);
        acc[r] = make_float4(0.f, 0.f, 0.f, 0.f);
    }
    float m = -INFINITY, l = 0.f;
    const float* fb = feat + ((size_t)b * S + ch * 64 + w * 16) * D;
    for (int i = 0; i < 16; ++i) {
        float4 f[4];
        #pragma unroll
        for (int r = 0; r < 4; ++r)
            f[r] = *reinterpret_cast<const float4*>(&fb[(size_t)i * D + r * 256 + lane * 4]);
        float dot = 0.f;
        #pragma unroll
        for (int r = 0; r < 4; ++r)
            dot += f[r].x * aw[r].x + f[r].y * aw[r].y + f[r].z * aw[r].z + f[r].w * aw[r].w;
        dot = wave_sum_bc(dot);
        if (dot <= m) {
            float wg = expf(dot - m);
            l += wg;
            #pragma unroll
            for (int r = 0; r < 4; ++r) {
                acc[r].x += wg * f[r].x; acc[r].y += wg * f[r].y;
                acc[r].z += wg * f[r].z; acc[r].w += wg * f[r].w;
            }
        } else {
            float sc = expf(m - dot);
            l = l * sc + 1.f;
            #pragma unroll
            for (int r = 0; r < 4; ++r) {
                acc[r].x = acc[r].x * sc + f[r].x; acc[r].y = acc[r].y * sc + f[r].y;
                acc[r].z = acc[r].z * sc + f[r].z; acc[r].w = acc[r].w * sc + f[r].w;
            }
            m = dot;
        }
    }
    __shared__ float sacc[4][1024];
    __shared__ float sml[4][2];
    #pragma unroll
    for (int r = 0; r < 4; ++r)
        *reinterpret_cast<float4*>(&sacc[w][r * 256 + lane * 4]) = acc[r];
    if (lane == 0) { sml[w][0] = m; sml[w][1] = l; }
    __syncthreads();
    float m0 = sml[0][0], m1 = sml[1][0], m2 = sml[2][0], m3 = sml[3][0];
    float mg = fmaxf(fmaxf(m0, m1), fmaxf(m2, m3));
    float s0 = expf(m0 - mg), s1 = expf(m1 - mg), s2 = expf(m2 - mg), s3 = expf(m3 - mg);
    int c = tid * 4;
    float4 a0 = *reinterpret_cast<float4*>(&sacc[0][c]);
    float4 a1 = *reinterpret_cast<float4*>(&sacc[1][c]);
    float4 a2 = *reinterpret_cast<float4*>(&sacc[2][c]);
    float4 a3 = *reinterpret_cast<float4*>(&sacc[3][c]);
    float4 o;
    o.x = s0 * a0.x + s1 * a1.x + s2 * a2.x + s3 * a3.x;
    o.y = s0 * a0.y + s1 * a1.y + s2 * a2.y + s3 * a3.y;
    o.z = s0 * a0.z + s1 * a1.z + s2 * a2.z + s3 * a3.z;
    o.w = s0 * a0.w + s1 * a1.w + s2 * a2.w + s3 * a3.w;
    *reinterpret_cast<float4*>(&part[((size_t)b * 16 + ch) * D + c]) = o;
    if (tid == 0) {
        float lg = s0 * sml[0][1] + s1 * sml[1][1] + s2 * sml[2][1] + s3 * sml[3][1];
        ml[(b * 16 + ch) * 2] = mg;
        ml[(b * 16 + ch) * 2 + 1] = lg;
    }
}

__global__ void k_pool_comb(const float* __restrict__ part, const float* __restrict__ ml,
                            float* __restrict__ pooled) {
    int b = blockIdx.x, tid = threadIdx.x;
    float mg = -INFINITY;
    #pragma unroll
    for (int i = 0; i < 16; ++i) mg = fmaxf(mg, ml[(b * 16 + i) * 2]);
    float denom = 0.f, sc[16];
    #pragma unroll
    for (int i = 0; i < 16; ++i) {
        sc[i] = expf(ml[(b * 16 + i) * 2] - mg);
        denom += sc[i] * ml[(b * 16 + i) * 2 + 1];
    }
    float inv = 1.f / denom;
    int c = tid * 4;
    float4 o = make_float4(0.f, 0.f, 0.f, 0.f);
    #pragma unroll
    for (int i = 0; i < 16; ++i) {
        float4 p = *reinterpret_cast<const float4*>(&part[((size_t)b * 16 + i) * D + c]);
        o.x += sc[i] * p.x; o.y += sc[i] * p.y; o.z += sc[i] * p.z; o.w += sc[i] * p.w;
    }
    o.x *= inv; o.y *= inv; o.z *= inv; o.w *= inv;
    *reinterpret_cast<float4*>(&pooled[(size_t)b * D + c]) = o;
}

// ---------------------------------------------------------------------------
// Pack W (row-major [TD][stride], cols 0..1023) into bf16 B-fragment order.
// Frag-block fid = (dt*3 + g)*32 + s; lane l holds W[g*1024+dt*16+(l&15)][s*32+(l>>4)*8 + j].
__global__ void k_packW(const float* __restrict__ Wsrc, short* __restrict__ dst, int stride) {
    int gid = blockIdx.x * 256 + threadIdx.x;   // < 6144*64
    int fid = gid >> 6, l = gid & 63;
    int s = fid & 31, g = (fid >> 5) % 3, dt = fid / 96;
    int row = g * 1024 + dt * 16 + (l & 15);
    int k0 = s * 32 + ((l >> 4) << 3);
    const float* src = Wsrc + (size_t)row * stride + k0;
    short v[8];
    #pragma unroll
    for (int j = 0; j < 8; ++j) v[j] = f2bf(src[j]);
    short* d = dst + ((size_t)fid * 64 + l) * 8;
    #pragma unroll
    for (int j = 0; j < 8; ++j) d[j] = v[j];
}

// Pack a [64][1024] fp32 matrix into bf16 A-fragment order.
// fid = m*32 + s; lane l holds A[m*16+(l&15)][s*32+(l>>4)*8 + j].
__global__ void k_packA(const float* __restrict__ Asrc, short* __restrict__ dst) {
    int gid = blockIdx.x * 256 + threadIdx.x;   // < 128*64
    int fid = gid >> 6, l = gid & 63;
    int m = fid >> 5, s = fid & 31;
    int row = m * 16 + (l & 15);
    int k0 = s * 32 + ((l >> 4) << 3);
    const float4 f0 = *reinterpret_cast<const float4*>(&Asrc[(size_t)row * 1024 + k0]);
    const float4 f1 = *reinterpret_cast<const float4*>(&Asrc[(size_t)row * 1024 + k0 + 4]);
    short* d = dst + ((size_t)fid * 64 + l) * 8;
    d[0] = f2bf(f0.x); d[1] = f2bf(f0.y); d[2] = f2bf(f0.z); d[3] = f2bf(f0.w);
    d[4] = f2bf(f1.x); d[5] = f2bf(f1.y); d[6] = f2bf(f1.z); d[7] = f2bf(f1.w);
}

__global__ void k_wscore(const float* __restrict__ W_ih, float* __restrict__ wscore) {
    int j = blockIdx.x * 256 + threadIdx.x;
    if (j < TD) wscore[j] = W_ih[(size_t)j * (D + 1) + D];
}

// ---------------------------------------------------------------------------
// gi0 = pooled @ W_ih[:, :D]^T + b_ih   (bf16 MFMA). Grid 128 = (dt 0..63, bh 0..1)
// XCD-pinned. 4 waves = k-quarters. Block output: 32 b x 48 cols.
__global__ void k_gi0_mfma(const s8v* __restrict__ Bp, const s8v* __restrict__ Ap,
                           const float* __restrict__ b_ih, float* __restrict__ gi0) {
    __shared__ float psum[4][32][49];
    int tid = threadIdx.x, w = tid >> 6, l = tid & 63;
    int n = blockIdx.x, xcd = n & 7, i = n >> 3;
    int dt = xcd * 8 + (i & 7), bh = i >> 3;
    f4v acc[2][3];
    #pragma unroll
    for (int mi = 0; mi < 2; ++mi)
        #pragma unroll
        for (int g = 0; g < 3; ++g) acc[mi][g] = (f4v){0.f, 0.f, 0.f, 0.f};
    for (int s8 = 0; s8 < 8; ++s8) {
        int s = w * 8 + s8;
        s8v a0 = Ap[(size_t)((bh * 2 + 0) * 32 + s) * 64 + l];
        s8v a1 = Ap[(size_t)((bh * 2 + 1) * 32 + s) * 64 + l];
        s8v b0 = Bp[(size_t)((dt * 3 + 0) * 32 + s) * 64 + l];
        s8v b1 = Bp[(size_t)((dt * 3 + 1) * 32 + s) * 64 + l];
        s8v b2 = Bp[(size_t)((dt * 3 + 2) * 32 + s) * 64 + l];
        acc[0][0] = __builtin_amdgcn_mfma_f32_16x16x32_bf16(a0, b0, acc[0][0], 0, 0, 0);
        acc[0][1] = __builtin_amdgcn_mfma_f32_16x16x32_bf16(a0, b1, acc[0][1], 0, 0, 0);
        acc[0][2] = __builtin_amdgcn_mfma_f32_16x16x32_bf16(a0, b2, acc[0][2], 0, 0, 0);
        acc[1][0] = __builtin_amdgcn_mfma_f32_16x16x32_bf16(a1, b0, acc[1][0], 0, 0, 0);
        acc[1][1] = __builtin_amdgcn_mfma_f32_16x16x32_bf16(a1, b1, acc[1][1], 0, 0, 0);
        acc[1][2] = __builtin_amdgcn_mfma_f32_16x16x32_bf16(a1, b2, acc[1][2], 0, 0, 0);
    }
    #pragma unroll
    for (int mi = 0; mi < 2; ++mi)
        #pragma unroll
        for (int g = 0; g < 3; ++g)
            #pragma unroll
            for (int r = 0; r < 4; ++r)
                psum[w][mi * 16 + (l >> 4) * 4 + r][g * 16 + (l & 15)] = acc[mi][g][r];
    __syncthreads();
    int lb = tid & 31, b = bh * 32 + lb;
    #pragma unroll
    for (int pp = 0; pp < 2; ++pp) {
        int ld = (tid >> 5) + pp * 8;
        #pragma unroll
        for (int g = 0; g < 3; ++g) {
            int c48 = g * 16 + ld;
            float v = psum[0][lb][c48] + psum[1][lb][c48] + psum[2][lb][c48] + psum[3][lb][c48];
            int col = g * 1024 + dt * 16 + ld;
            gi0[(size_t)b * TD + col] = v + b_ih[col];
        }
    }
}

// ---------------------------------------------------------------------------
// One GRU step: gh-GEMM (bf16 MFMA) + fused gate epilogue.
// Grid 128 = (dt 0..63, bh 0..1) XCD-pinned; 4 waves = k-quarters.
// t==0 skips GEMM (h=0 -> gh = b_hh), score=0.
__global__ void k_step(const s8v* __restrict__ Bp, const s8v* __restrict__ Ap_in,
                       short* __restrict__ Ap_out, float* __restrict__ hf,
                       const float* __restrict__ gi0, const float* __restrict__ wscore,
                       const float* __restrict__ b_hh, const float* __restrict__ W_out,
                       const float* __restrict__ b_out, float* __restrict__ spart, int t) {
    __shared__ float psum[4][32][49];
    __shared__ float sredS[32][8];
    __shared__ float sredO[256];
    int tid = threadIdx.x, w = tid >> 6, l = tid & 63;
    int n = blockIdx.x, xcd = n & 7, i = n >> 3;
    int dt = xcd * 8 + (i & 7), bh = i >> 3;

    if (t > 0) {  // pre-reduce previous step's score partials
        int lb0 = tid & 31, grp = tid >> 5;
        const float* sp = spart + ((size_t)(t - 1) * B + bh * 32 + lb0) * 64 + grp * 8;
        float sv = 0.f;
        #pragma unroll
        for (int q = 0; q < 8; ++q) sv += sp[q];
        sredS[lb0][grp] = sv;
    }

    f4v acc[2][3];
    #pragma unroll
    for (int mi = 0; mi < 2; ++mi)
        #pragma unroll
        for (int g = 0; g < 3; ++g) acc[mi][g] = (f4v){0.f, 0.f, 0.f, 0.f};
    if (t > 0) {
        for (int s8 = 0; s8 < 8; ++s8) {
            int s = w * 8 + s8;
            s8v a0 = Ap_in[(size_t)((bh * 2 + 0) * 32 + s) * 64 + l];
            s8v a1 = Ap_in[(size_t)((bh * 2 + 1) * 32 + s) * 64 + l];
            s8v b0 = Bp[(size_t)((dt * 3 + 0) * 32 + s) * 64 + l];
            s8v b1 = Bp[(size_t)((dt * 3 + 1) * 32 + s) * 64 + l];
            s8v b2 = Bp[(size_t)((dt * 3 + 2) * 32 + s) * 64 + l];
            acc[0][0] = __builtin_amdgcn_mfma_f32_16x16x32_bf16(a0, b0, acc[0][0], 0, 0, 0);
            acc[0][1] = __builtin_amdgcn_mfma_f32_16x16x32_bf16(a0, b1, acc[0][1], 0, 0, 0);
            acc[0][2] = __builtin_amdgcn_mfma_f32_16x16x32_bf16(a0, b2, acc[0][2], 0, 0, 0);
            acc[1][0] = __builtin_amdgcn_mfma_f32_16x16x32_bf16(a1, b0, acc[1][0], 0, 0, 0);
            acc[1][1] = __builtin_amdgcn_mfma_f32_16x16x32_bf16(a1, b1, acc[1][1], 0, 0, 0);
            acc[1][2] = __builtin_amdgcn_mfma_f32_16x16x32_bf16(a1, b2, acc[1][2], 0, 0, 0);
        }
    }
    #pragma unroll
    for (int mi = 0; mi < 2; ++mi)
        #pragma unroll
        for (int g = 0; g < 3; ++g)
            #pragma unroll
            for (int r = 0; r < 4; ++r)
                psum[w][mi * 16 + (l >> 4) * 4 + r][g * 16 + (l & 15)] = acc[mi][g][r];
    __syncthreads();

    int lb = tid & 31, b = bh * 32 + lb;
    float score = 0.f;
    if (t > 0) {
        float ssum = b_out[0];
        #pragma unroll
        for (int g = 0; g < 8; ++g) ssum += sredS[lb][g];
        score = sigm(ssum);
    }
    float osum = 0.f;
    #pragma unroll
    for (int pp = 0; pp < 2; ++pp) {
        int ld = (tid >> 5) + pp * 8;
        int d = dt * 16 + ld;
        float ghr = b_hh[d], ghz = b_hh[D + d], ghn = b_hh[2 * D + d];
        if (t > 0) {
            #pragma unroll
            for (int ww = 0; ww < 4; ++ww) {
                ghr += psum[ww][lb][ld];
                ghz += psum[ww][lb][16 + ld];
                ghn += psum[ww][lb][32 + ld];
            }
        }
        const float* gb = gi0 + (size_t)b * TD;
        float gir = gb[d]           + score * wscore[d];
        float giz = gb[D + d]       + score * wscore[D + d];
        float gin = gb[2 * D + d]   + score * wscore[2 * D + d];
        float rr = sigm(gir + ghr);
        float zz = sigm(giz + ghz);
        float nn = tanhf(gin + rr * ghn);
        float hprev = (t > 0) ? hf[(size_t)b * D + d] : 0.f;
        float hnew = (1.f - zz) * nn + zz * hprev;
        hf[(size_t)b * D + d] = hnew;
        // scatter into next step's A-fragment layout
        int m = b >> 4, s = d >> 5, lane2 = (b & 15) + (((d >> 3) & 3) << 4), j = d & 7;
        Ap_out[(((size_t)m * 32 + s) * 64 + lane2) * 8 + j] = f2bf(hnew);
        osum += hnew * W_out[d];
    }
    sredO[tid] = osum;
    __syncthreads();
    if (tid < 32) {
        float v = sredO[tid];
        #pragma unroll
        for (int q = 1; q < 8; ++q) v += sredO[tid + q * 32];
        spart[((size_t)t * B + bh * 32 + tid) * 64 + dt] = v;
    }
}

__global__ void k_final(const float* __restrict__ spart, const float* __restrict__ b_out,
                        float* __restrict__ out) {
    int i = blockIdx.x * 256 + threadIdx.x;
    if (i >= B * C) return;
    int b = i / C, t = i % C;
    float s = b_out[0];
    const float* sp = spart + ((size_t)t * B + b) * 64;
    #pragma unroll
    for (int k = 0; k < 64; ++k) s += sp[k];
    out[i] = sigm(s);
}

extern "C" void kernel_launch(void* const* d_in, const int* in_sizes, int n_in,
                              void* d_out, int out_size, void* d_ws, size_t ws_size,
                              hipStream_t stream) {
    const float* feat  = (const float*)d_in[0];
    const float* a_w   = (const float*)d_in[1];
    const float* W_ih  = (const float*)d_in[2];
    const float* W_hh  = (const float*)d_in[3];
    const float* b_ih  = (const float*)d_in[4];
    const float* b_hh  = (const float*)d_in[5];
    const float* W_out = (const float*)d_in[6];
    const float* b_out = (const float*)d_in[7];
    float* out = (float*)d_out;
    float* ws = (float*)d_ws;

    float* part    = ws;                           // 1,048,576
    float* ml      = part + (size_t)B * 16 * D;    // 2048
    float* pooled  = ml + B * 16 * 2;              // 65,536
    float* gi0     = pooled + B * D;               // 196,608
    float* hf      = gi0 + (size_t)B * TD;         // 65,536
    float* spart   = hf + B * D;                   // C*B*64 = 40,960
    float* wscore  = spart + (size_t)C * B * 64;   // 3072
    short* pooledP = (short*)(wscore + TD);        // 65,536 sh
    short* hp0     = pooledP + (size_t)B * D;      // 65,536 sh
    short* hp1     = hp0 + (size_t)B * D;          // 65,536 sh
    short* BihP    = hp1 + (size_t)B * D;          // 3,145,728 sh
    short* BhhP    = BihP + (size_t)D * TD;        // 3,145,728 sh

    k_pool_part<<<dim3(16, B), 256, 0, stream>>>(feat, a_w, part, ml);
    k_pool_comb<<<dim3(B), 256, 0, stream>>>(part, ml, pooled);
    k_packA<<<dim3(32), 256, 0, stream>>>(pooled, pooledP);
    k_packW<<<dim3(1536), 256, 0, stream>>>(W_ih, BihP, D + 1);
    k_packW<<<dim3(1536), 256, 0, stream>>>(W_hh, BhhP, D);
    k_wscore<<<dim3(12), 256, 0, stream>>>(W_ih, wscore);
    k_gi0_mfma<<<dim3(128), 256, 0, stream>>>((const s8v*)BihP, (const s8v*)pooledP, b_ih, gi0);

    short* hp[2] = {hp0, hp1};
    for (int t = 0; t < C; ++t) {
        // t reads hp[t&1] (unused at t=0), writes hp[(t+1)&1]
        k_step<<<dim3(128), 256, 0, stream>>>((const s8v*)BhhP, (const s8v*)hp[t & 1],
                                              hp[(t + 1) & 1], hf, gi0, wscore, b_hh,
                                              W_out, b_out, spart, t);
    }
    k_final<<<dim3((B * C + 255) / 256), 256, 0, stream>>>(spart, b_out, out);
}